// Round 8
// baseline (148.245 us; speedup 1.0000x reference)
//
#include <hip/hip_runtime.h>
#include <hip/hip_bf16.h>

#define NWIN 4096
#define LW   64
#define DIM  128

typedef __attribute__((ext_vector_type(8))) short bf8;   // 8 x bf16
typedef __attribute__((ext_vector_type(4))) float f4;    // MFMA C/D

#define MFMA(a,b,c) __builtin_amdgcn_mfma_f32_16x16x32_bf16((a),(b),(c),0,0,0)

__device__ __forceinline__ unsigned short bfr(float f){
  __hip_bfloat16 h = __float2bfloat16(f);
  union { __hip_bfloat16 h; unsigned short u; } x; x.h = h; return x.u;
}
__device__ __forceinline__ unsigned long long pack4f(float a,float b,float c,float d){
  float2 lo2; lo2.x = a; lo2.y = b;
  float2 hi2; hi2.x = c; hi2.y = d;
  union { __hip_bfloat162 h[2]; unsigned long long u; } x;
  x.h[0] = __float22bfloat162_rn(lo2);
  x.h[1] = __float22bfloat162_rn(hi2);
  return x.u;
}
__device__ __forceinline__ bf8 mk_bf8(unsigned long long lo, unsigned long long hi){
  union { unsigned long long q[2]; bf8 v; } u; u.q[0]=lo; u.q[1]=hi; return u.v;
}

// ---- k-permuted frag layout (rs=256 buffers: Xq, Xf, CTX) ---------------
// Element k stored at byte 64*(k>>5) + 16*((k>>2)&3) + 8*((k>>4)&1) + 2*(k&3)
// within the row (XOR-swizzled by (row&7)<<4). A lane's 8-elem MFMA frag
// (k = kt*32 + 4*lq + {0..3} + {0,16}) is then 16 CONTIGUOUS bytes ->
// single aligned ds_read_b128 with zero bank-conflict overhead.
__device__ __forceinline__ bf8 frag_ldsx(const char* sm, int off,
                                         int rowBase, int kb, int l15, int lq){
  int row = rowBase + l15;
  int sw = (row & 7) << 4;
  return *(const bf8*)(sm + off + row*256 + ((kb + 16*lq) ^ sw));
}

// Old 2xb64 fragment read (kept for the VT buffer, rs=128)
__device__ __forceinline__ bf8 frag_lds(const char* sm, int off, int rs,
                                        int rowBase, int kb, int l15, int lq){
  int row = rowBase + l15;
  int sw = (row & 7) << 4;
  unsigned long long lo = *(const unsigned long long*)(sm + off + row*rs + ((kb + 8*lq) ^ sw));
  unsigned long long hi = *(const unsigned long long*)(sm + off + row*rs + ((kb + 8*lq + 32) ^ sw));
  union { unsigned long long q[2]; bf8 v; } u; u.q[0]=lo; u.q[1]=hi; return u.v;
}

// ---- weights -> fragment-ordered bf16 -----------------------------------
// dst idx = (((p*4+kt)*8+nt)*64 + lane)*8 + e ; p: 0=Wq 1=Wk 2=Wv 3=ow
// Lane l elem e holds W[nt*16 + (l&15)][kt*32 + 4*(l>>4) + (e&3) + 16*(e>>2)]
// — usable as BOTH an A-frag (m=out-dim) and a B-frag (n=out-dim).
__global__ void wfrag_kernel(const float* __restrict__ in_w,
                             const float* __restrict__ ow,
                             unsigned short* __restrict__ dst){
  int t = blockIdx.x * blockDim.x + threadIdx.x;
  if (t >= 4*4*8*64*8) return;
  int e  = t & 7;
  int l  = (t >> 3) & 63;
  int nt = (t >> 9) & 7;
  int kt = (t >> 12) & 3;
  int p  = t >> 14;
  int k = kt*32 + 4*(l >> 4) + (e & 3) + 16*(e >> 2);
  int n = nt*16 + (l & 15);
  float v = (p < 3) ? in_w[(p*128 + n)*128 + k] : ow[n*128 + k];
  dst[t] = bfr(v);
}

// ---- main: one block per window, 4 waves, 32KB LDS, 3 barriers ----------
// Q/K never touch LDS (swapped GEMM; C-frags ARE the QK^T operand frags).
// Length mask rides k-dim 16 of the QK^T MFMA. Softmax in exp2 domain
// (log2e folded into Q prescale), no max pass (masked = 2^-1e9 = 0),
// normalization deferred through PV (linear), v_rcp divide. Xq/Xf/CTX use
// the k-permuted layout -> all GEMM A-frags are single ds_read_b128.
// Buffers: B0: Xq -> VT ; B1: Xf -> CTX.
__launch_bounds__(256, 4)
__global__ void win_attn_mfma(const float* __restrict__ feat,
                              const float* __restrict__ pos,
                              const float* __restrict__ in_b,
                              const float* __restrict__ ob,
                              const unsigned char* __restrict__ maskb,
                              const int mask_is_byte,
                              const unsigned short* __restrict__ wf,
                              float* __restrict__ out){
  extern __shared__ char sm[];
  const int n    = blockIdx.x;
  const int tid  = threadIdx.x;
  const int wave = tid >> 6, lane = tid & 63, l15 = lane & 15, lq = lane >> 4;

  const int B0 = 0, B1 = 16384;
  const f4 fzero = {0.f, 0.f, 0.f, 0.f};

  // ---- stage Xq = bf16(feat+pos) -> B0, Xf = bf16(feat) -> B1 ------------
  // 4 consecutive k = 4q..4q+3 land contiguously at the permuted offset.
  const float* fb = feat + (size_t)n * (LW*DIM);
  const float* pb = pos  + (size_t)n * (LW*DIM);
  #pragma unroll
  for (int it = 0; it < 8; ++it){
    int j = tid + it*256; int r = j >> 5, q = j & 31;
    float4 f = *(const float4*)(fb + r*DIM + q*4);
    float4 p = *(const float4*)(pb + r*DIM + q*4);
    int sw = (r & 7) << 4;
    int wpos = 64*(q >> 3) + 16*(q & 3) + 8*((q >> 2) & 1);
    *(unsigned long long*)(sm + B1 + r*256 + (wpos ^ sw)) = pack4f(f.x, f.y, f.z, f.w);
    *(unsigned long long*)(sm + B0 + r*256 + (wpos ^ sw)) =
        pack4f(f.x + p.x, f.y + p.y, f.z + p.z, f.w + p.w);
  }
  // per-wave window length
  int mv = mask_is_byte ? (int)maskb[(size_t)n*LW + lane]
                        : ((const int*)maskb)[(size_t)n*LW + lane];
  unsigned long long bal = __ballot(mv != 0);
  const int len = bal ? (int)__builtin_ctzll(bal) : LW;
  // bias vectors for own heads (latency hidden under the barrier)
  float4 bq4[2], bk4[2];
  #pragma unroll
  for (int hh = 0; hh < 2; ++hh){
    int h = wave + 4*hh;
    bq4[hh] = *(const float4*)(in_b + h*16 + 4*lq);
    bk4[hh] = *(const float4*)(in_b + 128 + h*16 + 4*lq);
  }
  __syncthreads();                        // (1) staging complete

  // ---- pass 1: Q^T, K^T via swapped GEMM (reads B0 Xq) -------------------
  // Q prescale folds 1/sqrt(16) AND log2(e): softmax runs in exp2 domain.
  const float QSCALE = 0.25f * 1.4426950408889634f;
  unsigned long long q8lo[2][4], k8lo[2][4];
  {
    f4 qT[2][4], kT[2][4];
    #pragma unroll
    for (int hh = 0; hh < 2; ++hh)
      #pragma unroll
      for (int nt = 0; nt < 4; ++nt){ qT[hh][nt] = fzero; kT[hh][nt] = fzero; }
    #pragma unroll
    for (int kt = 0; kt < 4; ++kt){
      bf8 wq[2], wk[2];
      #pragma unroll
      for (int hh = 0; hh < 2; ++hh){
        int h = wave + 4*hh;
        wq[hh] = *(const bf8*)(wf + (size_t)(((0*4 + kt)*8 + h)*64 + lane)*8);
        wk[hh] = *(const bf8*)(wf + (size_t)(((1*4 + kt)*8 + h)*64 + lane)*8);
      }
      bf8 x[4];
      #pragma unroll
      for (int nt = 0; nt < 4; ++nt)
        x[nt] = frag_ldsx(sm, B0, nt*16, kt*64, l15, lq);
      #pragma unroll
      for (int hh = 0; hh < 2; ++hh)
        #pragma unroll
        for (int nt = 0; nt < 4; ++nt){
          qT[hh][nt] = MFMA(wq[hh], x[nt], qT[hh][nt]);
          kT[hh][nt] = MFMA(wk[hh], x[nt], kT[hh][nt]);
        }
    }
    // C-frag (dim=4lq+r, token=l15) -> bf16 lo-half frags, bias folded
    #pragma unroll
    for (int hh = 0; hh < 2; ++hh)
      #pragma unroll
      for (int nt = 0; nt < 4; ++nt){
        q8lo[hh][nt] = pack4f((qT[hh][nt][0] + bq4[hh].x) * QSCALE,
                              (qT[hh][nt][1] + bq4[hh].y) * QSCALE,
                              (qT[hh][nt][2] + bq4[hh].z) * QSCALE,
                              (qT[hh][nt][3] + bq4[hh].w) * QSCALE);
        k8lo[hh][nt] = pack4f(kT[hh][nt][0] + bk4[hh].x,
                              kT[hh][nt][1] + bk4[hh].y,
                              kT[hh][nt][2] + bk4[hh].z,
                              kT[hh][nt][3] + bk4[hh].w);
      }
  }

  // ---- pass 2: V^T (reads B1 Xf) -----------------------------------------
  f4 aV[2][4];
  #pragma unroll
  for (int g = 0; g < 2; ++g)
    #pragma unroll
    for (int nt = 0; nt < 4; ++nt) aV[g][nt] = fzero;
  #pragma unroll
  for (int kt = 0; kt < 4; ++kt){
    bf8 wv[2];
    #pragma unroll
    for (int g = 0; g < 2; ++g){
      int mt = wave + 4*g;
      wv[g] = *(const bf8*)(wf + (size_t)(((2*4 + kt)*8 + mt)*64 + lane)*8);
    }
    bf8 xf[4];
    #pragma unroll
    for (int nt = 0; nt < 4; ++nt)
      xf[nt] = frag_ldsx(sm, B1, nt*16, kt*64, l15, lq);
    #pragma unroll
    for (int g = 0; g < 2; ++g)
      #pragma unroll
      for (int nt = 0; nt < 4; ++nt)
        aV[g][nt] = MFMA(wv[g], xf[nt], aV[g][nt]);
  }
  __syncthreads();                        // (2) all Xq/Xf reads done

  // ---- VT scatter -> B0 (own rows; unchanged layout, rs=128) -------------
  #pragma unroll
  for (int g = 0; g < 2; ++g){
    int mt = wave + 4*g;
    #pragma unroll
    for (int r = 0; r < 4; ++r){
      int dim = mt*16 + 4*lq + r;
      float bv_ = in_b[256 + dim];
      #pragma unroll
      for (int nt = 0; nt < 4; ++nt){
        int col = nt*16 + l15;
        *(unsigned short*)(sm + B0 + dim*128 + ((col*2) ^ ((dim&7)<<4))) =
            bfr(aV[g][nt][r] + bv_);
      }
    }
  }

  // ---- attention: heads h in {wave, wave+4}, Q/K in registers ------------
  const unsigned long long qhi = (lq == 0) ? 0x3f80ull : 0ull;   // bf16 1.0 @ k=16
  unsigned long long khi[4];
  #pragma unroll
  for (int mt = 0; mt < 4; ++mt){
    float mval = (mt*16 + l15 < len) ? 0.f : -1e9f;
    khi[mt] = (lq == 0) ? (unsigned long long)bfr(mval) : 0ull;
  }

  #pragma unroll
  for (int hh = 0; hh < 2; ++hh){
    int h = wave + 4*hh;
    bf8 av0 = frag_lds(sm, B0, 128, h*16, 0,  l15, lq);
    bf8 av1 = frag_lds(sm, B0, 128, h*16, 64, l15, lq);
    #pragma unroll
    for (int nh = 0; nh < 2; ++nh){       // two query-tile halves
      f4 s[4][2];
      __builtin_amdgcn_s_setprio(1);
      #pragma unroll
      for (int mt = 0; mt < 4; ++mt)
        #pragma unroll
        for (int j = 0; j < 2; ++j)
          s[mt][j] = MFMA(mk_bf8(k8lo[hh][mt], khi[mt]),
                          mk_bf8(q8lo[hh][2*nh + j], qhi), fzero);
      __builtin_amdgcn_s_setprio(0);
      // softmax in exp2 domain, no max pass (masked = 2^-1e9 = 0),
      // normalization deferred through PV
      float inv[2];
      #pragma unroll
      for (int j = 0; j < 2; ++j){
        float ss = 0.f;
        #pragma unroll
        for (int mt = 0; mt < 4; ++mt)
          #pragma unroll
          for (int r = 0; r < 4; ++r){
            float p = __builtin_amdgcn_exp2f(s[mt][j][r]);
            s[mt][j][r] = p;
            ss += p;
          }
        ss += __shfl_xor(ss, 16);
        ss += __shfl_xor(ss, 32);
        inv[j] = __builtin_amdgcn_rcpf(ss);
      }
      // P^T C-frags ARE the PV^T B-frags (unnormalized P, bf16-safe)
      bf8 pb_[2][2];
      #pragma unroll
      for (int kt = 0; kt < 2; ++kt)
        #pragma unroll
        for (int j = 0; j < 2; ++j){
          unsigned long long lo = pack4f(s[2*kt  ][j][0], s[2*kt  ][j][1],
                                         s[2*kt  ][j][2], s[2*kt  ][j][3]);
          unsigned long long hi = pack4f(s[2*kt+1][j][0], s[2*kt+1][j][1],
                                         s[2*kt+1][j][2], s[2*kt+1][j][3]);
          union { unsigned long long q[2]; bf8 v; } u; u.q[0]=lo; u.q[1]=hi;
          pb_[kt][j] = u.v;
        }
      __builtin_amdgcn_s_setprio(1);
      #pragma unroll
      for (int j = 0; j < 2; ++j){
        f4 c = fzero;
        c = MFMA(av0, pb_[0][j], c);
        c = MFMA(av1, pb_[1][j], c);
        // normalize, pack 4 consecutive dims -> one b64 at the PERMUTED
        // position: dims h*16+4lq+{0..3} -> byte 64*(h>>1)+16*lq+8*(h&1)
        int row = (2*nh + j)*16 + l15;    // query
        unsigned long long w = pack4f(c[0]*inv[j], c[1]*inv[j],
                                      c[2]*inv[j], c[3]*inv[j]);
        *(unsigned long long*)(sm + B1 + row*256 +
            ((64*(h>>1) + 16*lq + 8*(h&1)) ^ ((row&7)<<4))) = w;
      }
      __builtin_amdgcn_s_setprio(0);
    }
  }
  __syncthreads();                        // (3) CTX all-to-all for out-proj

  // ---- out-proj: out = ctx @ ow^T + ob (ctx in B1, permuted layout) ------
  {
    f4 acc[4][2];
    #pragma unroll
    for (int mt = 0; mt < 4; ++mt)
      #pragma unroll
      for (int g = 0; g < 2; ++g) acc[mt][g] = fzero;
    #pragma unroll
    for (int kt = 0; kt < 4; ++kt){
      bf8 b[2];
      #pragma unroll
      for (int g = 0; g < 2; ++g){
        int nt = wave*2 + g;
        b[g] = *(const bf8*)(wf + (size_t)(((3*4 + kt)*8 + nt)*64 + lane)*8);
      }
      bf8 a[4];
      #pragma unroll
      for (int mt = 0; mt < 4; ++mt)
        a[mt] = frag_ldsx(sm, B1, mt*16, kt*64, l15, lq);
      #pragma unroll
      for (int g = 0; g < 2; ++g)
        #pragma unroll
        for (int mt = 0; mt < 4; ++mt)
          acc[mt][g] = MFMA(a[mt], b[g], acc[mt][g]);
    }
    float* op = out + (size_t)n * (LW*DIM);
    #pragma unroll
    for (int g = 0; g < 2; ++g){
      int nt = wave*2 + g;
      float bias = ob[nt*16 + l15];
      #pragma unroll
      for (int mt = 0; mt < 4; ++mt)
        #pragma unroll
        for (int r = 0; r < 4; ++r){
          int row = mt*16 + 4*lq + r;
          op[row*DIM + nt*16 + l15] = acc[mt][g][r] + bias;
        }
    }
  }
}

extern "C" void kernel_launch(void* const* d_in, const int* in_sizes, int n_in,
                              void* d_out, int out_size, void* d_ws, size_t ws_size,
                              hipStream_t stream){
  const float* feat = (const float*)d_in[0];
  const float* pos  = (const float*)d_in[1];
  const unsigned char* mask = (const unsigned char*)d_in[2];
  const float* in_w = (const float*)d_in[3];
  const float* in_b = (const float*)d_in[4];
  const float* ow   = (const float*)d_in[5];
  const float* ob   = (const float*)d_in[6];
  float* out = (float*)d_out;
  unsigned short* wf = (unsigned short*)d_ws;

  // Mask layout from buffer sizes (convention-independent ratio):
  // feat has 128 f32 per mask element -> feat_sz/mask_sz = 512 for 1-byte
  // bool, 128 for int32. Threshold at 256.
  const int mask_is_byte = (in_sizes[0] / in_sizes[2]) >= 256 ? 1 : 0;

  wfrag_kernel<<<(4*4*8*64*8 + 255)/256, 256, 0, stream>>>(in_w, ow, wf);
  win_attn_mfma<<<NWIN, 256, 32768, stream>>>(feat, pos, in_b, ob, mask,
                                              mask_is_byte, wf, out);
}

// Round 9
// 132.009 us; speedup vs baseline: 1.1230x; 1.1230x over previous
//
#include <hip/hip_runtime.h>
#include <hip/hip_bf16.h>

#define NWIN 4096
#define LW   64
#define DIM  128

typedef __attribute__((ext_vector_type(8))) short bf8;   // 8 x bf16
typedef __attribute__((ext_vector_type(4))) float f4;    // MFMA C/D

#define MFMA(a,b,c) __builtin_amdgcn_mfma_f32_16x16x32_bf16((a),(b),(c),0,0,0)

__device__ __forceinline__ unsigned short bfr(float f){
  __hip_bfloat16 h = __float2bfloat16(f);
  union { __hip_bfloat16 h; unsigned short u; } x; x.h = h; return x.u;
}
__device__ __forceinline__ unsigned long long pack4f(float a,float b,float c,float d){
  float2 lo2; lo2.x = a; lo2.y = b;
  float2 hi2; hi2.x = c; hi2.y = d;
  union { __hip_bfloat162 h[2]; unsigned long long u; } x;
  x.h[0] = __float22bfloat162_rn(lo2);
  x.h[1] = __float22bfloat162_rn(hi2);
  return x.u;
}
__device__ __forceinline__ bf8 mk_bf8(unsigned long long lo, unsigned long long hi){
  union { unsigned long long q[2]; bf8 v; } u; u.q[0]=lo; u.q[1]=hi; return u.v;
}

// Fragment read from row-major swizzled LDS: rows rowBase+(lane&15),
// k bytes at kb+8*lq (elems 0-3) and +32 (elems 4-7). XOR-swizzle per row.
__device__ __forceinline__ bf8 frag_lds(const char* sm, int off, int rs,
                                        int rowBase, int kb, int l15, int lq){
  int row = rowBase + l15;
  int sw = (row & 7) << 4;
  unsigned long long lo = *(const unsigned long long*)(sm + off + row*rs + ((kb + 8*lq) ^ sw));
  unsigned long long hi = *(const unsigned long long*)(sm + off + row*rs + ((kb + 8*lq + 32) ^ sw));
  union { unsigned long long q[2]; bf8 v; } u; u.q[0]=lo; u.q[1]=hi; return u.v;
}

// ---- weights -> fragment-ordered bf16 -----------------------------------
// dst idx = (((p*4+kt)*8+nt)*64 + lane)*8 + e ; p: 0=Wq 1=Wk 2=Wv 3=ow
// Lane l elem e holds W[nt*16 + (l&15)][kt*32 + 4*(l>>4) + (e&3) + 16*(e>>2)]
// — usable as BOTH an A-frag (m=out-dim) and a B-frag (n=out-dim).
// Wq rows are pre-scaled by QSCALE = 0.25*log2(e): softmax runs in exp2
// domain with no per-element scaling in the main kernel.
__global__ void wfrag_kernel(const float* __restrict__ in_w,
                             const float* __restrict__ ow,
                             unsigned short* __restrict__ dst){
  int t = blockIdx.x * blockDim.x + threadIdx.x;
  if (t >= 4*4*8*64*8) return;
  int e  = t & 7;
  int l  = (t >> 3) & 63;
  int nt = (t >> 9) & 7;
  int kt = (t >> 12) & 3;
  int p  = t >> 14;
  int k = kt*32 + 4*(l >> 4) + (e & 3) + 16*(e >> 2);
  int n = nt*16 + (l & 15);
  float v = (p < 3) ? in_w[(p*128 + n)*128 + k] : ow[n*128 + k];
  if (p == 0) v *= 0.25f * 1.4426950408889634f;   // fold QK scale + log2e into Wq
  dst[t] = bfr(v);
}

// ---- main: one block per window, 4 waves, 32KB LDS, 3 barriers ----------
// Q/K never touch LDS (swapped GEMM; C-frags ARE the QK^T operand frags).
// Length mask rides k-dim 16 of the QK^T MFMA. Softmax in exp2 domain
// (QSCALE pre-folded into Wq/bq), no max pass (masked = 2^-1e9 = 0).
// Softmax DENOMINATOR via MFMA: csum = 1^T . P rides the matrix pipe
// (C-frag replicates the per-query sum into every lane) — no add tree,
// no cross-lane shuffles, and the sum overlaps the PV MFMAs.
// Normalization applied at CTX write; v_rcp divide.
// Buffers: B0: Xq -> VT ; B1: Xf -> CTX.
__launch_bounds__(256, 4)
__global__ void win_attn_mfma(const float* __restrict__ feat,
                              const float* __restrict__ pos,
                              const float* __restrict__ in_b,
                              const float* __restrict__ ob,
                              const unsigned char* __restrict__ maskb,
                              const int mask_is_byte,
                              const unsigned short* __restrict__ wf,
                              float* __restrict__ out){
  extern __shared__ char sm[];
  const int n    = blockIdx.x;
  const int tid  = threadIdx.x;
  const int wave = tid >> 6, lane = tid & 63, l15 = lane & 15, lq = lane >> 4;

  const int B0 = 0, B1 = 16384;
  const f4 fzero = {0.f, 0.f, 0.f, 0.f};

  // ---- stage Xq = bf16(feat+pos) -> B0, Xf = bf16(feat) -> B1 ------------
  const float* fb = feat + (size_t)n * (LW*DIM);
  const float* pb = pos  + (size_t)n * (LW*DIM);
  #pragma unroll
  for (int it = 0; it < 8; ++it){
    int j = tid + it*256; int r = j >> 5, q = j & 31;
    float4 f = *(const float4*)(fb + r*DIM + q*4);
    float4 p = *(const float4*)(pb + r*DIM + q*4);
    int sw = (r & 7) << 4;
    *(unsigned long long*)(sm + B1 + r*256 + ((q*8) ^ sw)) = pack4f(f.x, f.y, f.z, f.w);
    *(unsigned long long*)(sm + B0 + r*256 + ((q*8) ^ sw)) =
        pack4f(f.x + p.x, f.y + p.y, f.z + p.z, f.w + p.w);
  }
  // per-wave window length
  int mv = mask_is_byte ? (int)maskb[(size_t)n*LW + lane]
                        : ((const int*)maskb)[(size_t)n*LW + lane];
  unsigned long long bal = __ballot(mv != 0);
  const int len = bal ? (int)__builtin_ctzll(bal) : LW;
  // bias vectors for own heads (latency hidden under the barrier);
  // bq pre-scaled to match the pre-scaled Wq.
  const float QSCALE = 0.25f * 1.4426950408889634f;
  float4 bq4[2], bk4[2];
  #pragma unroll
  for (int hh = 0; hh < 2; ++hh){
    int h = wave + 4*hh;
    float4 b = *(const float4*)(in_b + h*16 + 4*lq);
    bq4[hh] = make_float4(b.x*QSCALE, b.y*QSCALE, b.z*QSCALE, b.w*QSCALE);
    bk4[hh] = *(const float4*)(in_b + 128 + h*16 + 4*lq);
  }
  __syncthreads();                        // (1) staging complete

  // ---- pass 1: Q^T, K^T via swapped GEMM (reads B0 Xq) -------------------
  unsigned long long q8lo[2][4], k8lo[2][4];
  {
    f4 qT[2][4], kT[2][4];
    #pragma unroll
    for (int hh = 0; hh < 2; ++hh)
      #pragma unroll
      for (int nt = 0; nt < 4; ++nt){ qT[hh][nt] = fzero; kT[hh][nt] = fzero; }
    #pragma unroll
    for (int kt = 0; kt < 4; ++kt){
      bf8 wq[2], wk[2];
      #pragma unroll
      for (int hh = 0; hh < 2; ++hh){
        int h = wave + 4*hh;
        wq[hh] = *(const bf8*)(wf + (size_t)(((0*4 + kt)*8 + h)*64 + lane)*8);
        wk[hh] = *(const bf8*)(wf + (size_t)(((1*4 + kt)*8 + h)*64 + lane)*8);
      }
      bf8 x[4];
      #pragma unroll
      for (int nt = 0; nt < 4; ++nt)
        x[nt] = frag_lds(sm, B0, 256, nt*16, kt*64, l15, lq);
      #pragma unroll
      for (int hh = 0; hh < 2; ++hh)
        #pragma unroll
        for (int nt = 0; nt < 4; ++nt){
          qT[hh][nt] = MFMA(wq[hh], x[nt], qT[hh][nt]);
          kT[hh][nt] = MFMA(wk[hh], x[nt], kT[hh][nt]);
        }
    }
    // C-frag (dim=4lq+r, token=l15) -> bf16 lo-half frags, bias folded
    #pragma unroll
    for (int hh = 0; hh < 2; ++hh)
      #pragma unroll
      for (int nt = 0; nt < 4; ++nt){
        q8lo[hh][nt] = pack4f(qT[hh][nt][0] + bq4[hh].x,
                              qT[hh][nt][1] + bq4[hh].y,
                              qT[hh][nt][2] + bq4[hh].z,
                              qT[hh][nt][3] + bq4[hh].w);
        k8lo[hh][nt] = pack4f(kT[hh][nt][0] + bk4[hh].x,
                              kT[hh][nt][1] + bk4[hh].y,
                              kT[hh][nt][2] + bk4[hh].z,
                              kT[hh][nt][3] + bk4[hh].w);
      }
  }

  // ---- pass 2: V^T (reads B1 Xf) -----------------------------------------
  f4 aV[2][4];
  #pragma unroll
  for (int g = 0; g < 2; ++g)
    #pragma unroll
    for (int nt = 0; nt < 4; ++nt) aV[g][nt] = fzero;
  #pragma unroll
  for (int kt = 0; kt < 4; ++kt){
    bf8 wv[2];
    #pragma unroll
    for (int g = 0; g < 2; ++g){
      int mt = wave + 4*g;
      wv[g] = *(const bf8*)(wf + (size_t)(((2*4 + kt)*8 + mt)*64 + lane)*8);
    }
    bf8 xf[4];
    #pragma unroll
    for (int nt = 0; nt < 4; ++nt)
      xf[nt] = frag_lds(sm, B1, 256, nt*16, kt*64, l15, lq);
    #pragma unroll
    for (int g = 0; g < 2; ++g)
      #pragma unroll
      for (int nt = 0; nt < 4; ++nt)
        aV[g][nt] = MFMA(wv[g], xf[nt], aV[g][nt]);
  }
  __syncthreads();                        // (2) all Xq/Xf reads done

  // ---- VT scatter -> B0 (own rows: dims of heads wave, wave+4) -----------
  #pragma unroll
  for (int g = 0; g < 2; ++g){
    int mt = wave + 4*g;
    #pragma unroll
    for (int r = 0; r < 4; ++r){
      int dim = mt*16 + 4*lq + r;
      float bv_ = in_b[256 + dim];
      #pragma unroll
      for (int nt = 0; nt < 4; ++nt){
        int col = nt*16 + l15;
        *(unsigned short*)(sm + B0 + dim*128 + ((col*2) ^ ((dim&7)<<4))) =
            bfr(aV[g][nt][r] + bv_);
      }
    }
  }

  // ---- attention: heads h in {wave, wave+4}, Q/K in registers ------------
  const unsigned long long qhi = (lq == 0) ? 0x3f80ull : 0ull;   // bf16 1.0 @ k=16
  unsigned long long khi[4];
  #pragma unroll
  for (int mt = 0; mt < 4; ++mt){
    float mval = (mt*16 + l15 < len) ? 0.f : -1e9f;
    khi[mt] = (lq == 0) ? (unsigned long long)bfr(mval) : 0ull;
  }
  const unsigned long long ONE4 = 0x3f803f803f803f80ull;   // 4 x bf16 1.0
  const bf8 ones8 = mk_bf8(ONE4, ONE4);

  #pragma unroll
  for (int hh = 0; hh < 2; ++hh){
    int h = wave + 4*hh;
    bf8 av0 = frag_lds(sm, B0, 128, h*16, 0,  l15, lq);
    bf8 av1 = frag_lds(sm, B0, 128, h*16, 64, l15, lq);
    #pragma unroll
    for (int nh = 0; nh < 2; ++nh){       // two query-tile halves
      f4 s[4][2];
      __builtin_amdgcn_s_setprio(1);
      #pragma unroll
      for (int mt = 0; mt < 4; ++mt)
        #pragma unroll
        for (int j = 0; j < 2; ++j)
          s[mt][j] = MFMA(mk_bf8(k8lo[hh][mt], khi[mt]),
                          mk_bf8(q8lo[hh][2*nh + j], qhi), fzero);
      __builtin_amdgcn_s_setprio(0);
      // exp2 only — no add tree, no shuffles (sum comes from the MFMA pipe)
      #pragma unroll
      for (int j = 0; j < 2; ++j)
        #pragma unroll
        for (int mt = 0; mt < 4; ++mt)
          #pragma unroll
          for (int r = 0; r < 4; ++r)
            s[mt][j][r] = __builtin_amdgcn_exp2f(s[mt][j][r]);
      // P^T C-frags ARE the PV^T B-frags (unnormalized P, bf16-safe)
      bf8 pb_[2][2];
      #pragma unroll
      for (int kt = 0; kt < 2; ++kt)
        #pragma unroll
        for (int j = 0; j < 2; ++j){
          unsigned long long lo = pack4f(s[2*kt  ][j][0], s[2*kt  ][j][1],
                                         s[2*kt  ][j][2], s[2*kt  ][j][3]);
          unsigned long long hi = pack4f(s[2*kt+1][j][0], s[2*kt+1][j][1],
                                         s[2*kt+1][j][2], s[2*kt+1][j][3]);
          union { unsigned long long q[2]; bf8 v; } u; u.q[0]=lo; u.q[1]=hi;
          pb_[kt][j] = u.v;
        }
      __builtin_amdgcn_s_setprio(1);
      #pragma unroll
      for (int j = 0; j < 2; ++j){
        f4 c = fzero, cs = fzero;
        c  = MFMA(av0,   pb_[0][j], c);
        c  = MFMA(av1,   pb_[1][j], c);
        cs = MFMA(ones8, pb_[0][j], cs);    // 1^T.P : per-query sum,
        cs = MFMA(ones8, pb_[1][j], cs);    // replicated into every lane
        float inv = __builtin_amdgcn_rcpf(cs[0]);
        // normalize at write, pack 4 dims -> one b64
        int row = (2*nh + j)*16 + l15;      // query
        unsigned long long w = pack4f(c[0]*inv, c[1]*inv, c[2]*inv, c[3]*inv);
        *(unsigned long long*)(sm + B1 + row*256 +
            ((32*h + 8*lq) ^ ((row&7)<<4))) = w;
      }
      __builtin_amdgcn_s_setprio(0);
    }
  }
  __syncthreads();                        // (3) CTX all-to-all for out-proj

  // ---- out-proj: out = ctx @ ow^T + ob (ctx in B1) -----------------------
  {
    f4 acc[4][2];
    #pragma unroll
    for (int mt = 0; mt < 4; ++mt)
      #pragma unroll
      for (int g = 0; g < 2; ++g) acc[mt][g] = fzero;
    #pragma unroll
    for (int kt = 0; kt < 4; ++kt){
      bf8 b[2];
      #pragma unroll
      for (int g = 0; g < 2; ++g){
        int nt = wave*2 + g;
        b[g] = *(const bf8*)(wf + (size_t)(((3*4 + kt)*8 + nt)*64 + lane)*8);
      }
      bf8 a[4];
      #pragma unroll
      for (int mt = 0; mt < 4; ++mt)
        a[mt] = frag_lds(sm, B1, 256, mt*16, kt*64, l15, lq);
      #pragma unroll
      for (int g = 0; g < 2; ++g)
        #pragma unroll
        for (int mt = 0; mt < 4; ++mt)
          acc[mt][g] = MFMA(a[mt], b[g], acc[mt][g]);
    }
    float* op = out + (size_t)n * (LW*DIM);
    #pragma unroll
    for (int g = 0; g < 2; ++g){
      int nt = wave*2 + g;
      float bias = ob[nt*16 + l15];
      #pragma unroll
      for (int mt = 0; mt < 4; ++mt)
        #pragma unroll
        for (int r = 0; r < 4; ++r){
          int row = mt*16 + 4*lq + r;
          op[row*DIM + nt*16 + l15] = acc[mt][g][r] + bias;
        }
    }
  }
}

extern "C" void kernel_launch(void* const* d_in, const int* in_sizes, int n_in,
                              void* d_out, int out_size, void* d_ws, size_t ws_size,
                              hipStream_t stream){
  const float* feat = (const float*)d_in[0];
  const float* pos  = (const float*)d_in[1];
  const unsigned char* mask = (const unsigned char*)d_in[2];
  const float* in_w = (const float*)d_in[3];
  const float* in_b = (const float*)d_in[4];
  const float* ow   = (const float*)d_in[5];
  const float* ob   = (const float*)d_in[6];
  float* out = (float*)d_out;
  unsigned short* wf = (unsigned short*)d_ws;

  // Mask layout from buffer sizes (convention-independent ratio):
  // feat has 128 f32 per mask element -> feat_sz/mask_sz = 512 for 1-byte
  // bool, 128 for int32. Threshold at 256.
  const int mask_is_byte = (in_sizes[0] / in_sizes[2]) >= 256 ? 1 : 0;

  wfrag_kernel<<<(4*4*8*64*8 + 255)/256, 256, 0, stream>>>(in_w, ow, wf);
  win_attn_mfma<<<NWIN, 256, 32768, stream>>>(feat, pos, in_b, ob, mask,
                                              mask_is_byte, wf, out);
}